// Round 7
// baseline (270.369 us; speedup 1.0000x reference)
//
#include <hip/hip_runtime.h>

#define BATCH      4096
#define OBS_COLS   2304
#define OTH_OFF    2048
#define EMB        256
#define OUTC       512

// ws layout: fold floats (8 KB) | packed bf16 B-fragment slices (82 x 8 KB)
#define FOLD_BYTES 8192u

typedef __bf16 bf16x8 __attribute__((ext_vector_type(8)));
typedef __bf16 bf16x4 __attribute__((ext_vector_type(4)));
typedef float  f32x16 __attribute__((ext_vector_type(16)));

// Slice bases (units of 512 bf16x8 = one 16x256 K-step slice) within wp
#define S_PW1  0
#define S_PW2  2
#define S_PW3  18
#define S_OW1  34
#define S_OW2  50
#define S_WQK  66

// Swizzled element index into a [rows][256] bf16 LDS tile.
__device__ __forceinline__ int shx(int row, int col) {
    return (row << 8) + ((((col >> 3) ^ (row & 31)) << 3) | (col & 7));
}

// ---------------------------------------------------------------------------
// k_prep: 83 WGs.
//  WG 0..81: pack one 16x256 K-step slice as bf16 B-fragments:
//    pW1(zero-pad,2) pW2(16) pW3(16) oW1(16) oW2(16) WQK(16, folded Wq.Wk)
//  WG 82: fold vectors: bqk[n]=Wk[h][d].bq-slice, wqb[c][h]=Wq-row.bk[h],
//    qbc[h]=bq-slice.bk[h].
// frag elem j of (ct,lane): W[kt*16 + (lane>>5)*8 + j][ct*32 + (lane&31)].
// ---------------------------------------------------------------------------
__global__ __launch_bounds__(512) void k_prep(
    const float* __restrict__ pW1, const float* __restrict__ pW2,
    const float* __restrict__ pW3, const float* __restrict__ oW1,
    const float* __restrict__ oW2, const float* __restrict__ Wq,
    const float* __restrict__ Wk,  const float* __restrict__ bq,
    const float* __restrict__ bk,
    float* __restrict__ fold, __bf16* __restrict__ wp)
{
    const int s = blockIdx.x;
    const int t = threadIdx.x;
    if (s < 82) {
        const int ct = t >> 6, lane = t & 63;
        const int n  = ct * 32 + (lane & 31);
        bf16x8 v;
        if (s < S_WQK) {
            int kt; const float* W; int isW1 = 0;
            if      (s < S_PW2) { kt = s;         W = pW1; isW1 = 1; }
            else if (s < S_PW3) { kt = s - S_PW2; W = pW2; }
            else if (s < S_OW1) { kt = s - S_PW3; W = pW3; }
            else if (s < S_OW2) { kt = s - S_OW1; W = oW1; }
            else                { kt = s - S_OW2; W = oW2; }
            const int kbase = kt * 16 + (lane >> 5) * 8;
            #pragma unroll
            for (int j = 0; j < 8; ++j) {
                const int k = kbase + j;
                const float f = (isW1 && k >= 31) ? 0.0f : W[k * 256 + n];
                v[j] = (__bf16)f;
            }
        } else {
            // WQK fold: WQK[c][n] = sum_e Wq[c][(n&~63)+e] * Wk[h][d][e]
            const int kt = s - S_WQK;
            const int kbase = kt * 16 + (lane >> 5) * 8;
            const int h = n >> 6, d = n & 63;
            const int qb_ = n & ~63;
            const float* wk = Wk + (size_t)h * 4096 + (size_t)d * 64;
            float acc[8];
            #pragma unroll
            for (int j = 0; j < 8; ++j) acc[j] = 0.0f;
            for (int e = 0; e < 64; ++e) {
                const float wkv = wk[e];
                #pragma unroll
                for (int j = 0; j < 8; ++j)
                    acc[j] += Wq[(size_t)(kbase + j) * 256 + qb_ + e] * wkv;
            }
            #pragma unroll
            for (int j = 0; j < 8; ++j) v[j] = (__bf16)acc[j];
        }
        ((bf16x8*)wp)[(size_t)s * 512 + t] = v;
    } else {
        // fold vectors
        if (t < 256) {      // bqk
            const int h = t >> 6, d = t & 63;
            const float* wk = Wk + (size_t)h * 4096 + (size_t)d * 64;
            const float* bqs = bq + (t & ~63);
            float a = 0.0f;
            for (int e = 0; e < 64; ++e) a += wk[e] * bqs[e];
            fold[t] = a;
        }
        #pragma unroll
        for (int i = 0; i < 2; ++i) {   // wqb[c][h] at fold[256 + c*4 + h]
            const int idx = i * 512 + t;
            const int c = idx >> 2, h = idx & 3;
            float a = 0.0f;
            for (int e = 0; e < 64; ++e)
                a += Wq[(size_t)c * 256 + h * 64 + e] * bk[h * 64 + e];
            fold[256 + idx] = a;
        }
        if (t < 4) {        // qbc
            float a = 0.0f;
            for (int e = 0; e < 64; ++e) a += bq[t * 64 + e] * bk[t * 64 + e];
            fold[1280 + t] = a;
        }
    }
}

// ---------------------------------------------------------------------------
// k_obj (fused): 2048 WGs x 512 thr, 2 batch rows/WG, ~79 KB LDS -> 2 WG/CU.
//  O-phase (per-WG others-MLP on a 32-row tile, rows 0..1 valid):
//    O-L1: relu(oth@oW1+b1) -> s_h rows 64..95
//    O-L2: (.)@oW2+b2 -> out[:, :256] (rows 0,1) + bf16 s_h rows 96..127
//    O-L3: e@WQK+bqk -> s_qk ; qb = e@wqb+qbc -> s_qb
//  Then object MLP GEMM1/2/3 + softmax + folded-Wv epilogue as before.
// ---------------------------------------------------------------------------
__global__ __launch_bounds__(512, 4) void k_obj(
    const float* __restrict__ obs,  const __bf16* __restrict__ wp,
    const float* __restrict__ fold,
    const float* __restrict__ ob1,  const float* __restrict__ ob2,
    const float* __restrict__ pb1,  const float* __restrict__ pb2,
    const float* __restrict__ pb3,  const float* __restrict__ bv,
    const float* __restrict__ Wv,   float* __restrict__ out)
{
    __shared__ __align__(16) __bf16 s_h[128 * 256];   // 65536 B (swizzled)
    __shared__ __align__(16) char s_fp[128 * 40 * 2]; // 10240 B: feats, later p
    __bf16* s_f = (__bf16*)s_fp;
    float*  s_p = (float*)s_fp;
    __shared__ float s_mask[128];
    __shared__ float s_qk[8 * 64];
    __shared__ float s_am[8 * 64];
    __shared__ float s_amsum[8];
    __shared__ float s_qb[8];

    const int t  = threadIdx.x;
    const int b0 = blockIdx.x * 2;
    const int wv = t >> 6, lane = t & 63;
    const int lm = lane & 31, lh = lane >> 5;
    const int rtp = wv & 1;
    const int ct0 = (wv >> 1) * 2;
    const int row0 = rtp * 64 + lm;
    const int row1 = row0 + 32;
    const int ct = wv;                 // O-phase col tile

    // GEMM1 B-fragments: independent of staging, issue early
    bf16x8 b1[2][2];
    {
        const bf16x8* Bg = (const bf16x8*)wp + S_PW1 * 512;
        #pragma unroll
        for (int kt = 0; kt < 2; ++kt)
            #pragma unroll
            for (int c = 0; c < 2; ++c)
                b1[kt][c] = Bg[(kt * 8 + ct0 + c) * 64 + lane];
    }

    // ---- stage feats (128 x 32 bf16, stride 40) + mask ----
    {
        const int row = t >> 2, q4 = t & 3;
        const float* src = obs + (size_t)(b0 + (row >> 6)) * OBS_COLS
                               + (row & 63) * 32 + q4 * 8;
        const float4 v0 = ((const float4*)src)[0];
        const float4 v1 = ((const float4*)src)[1];
        bf16x8 o;
        o[0]=(__bf16)v0.x; o[1]=(__bf16)v0.y; o[2]=(__bf16)v0.z; o[3]=(__bf16)v0.w;
        o[4]=(__bf16)v1.x; o[5]=(__bf16)v1.y; o[6]=(__bf16)v1.z; o[7]=(__bf16)v1.w;
        *(bf16x8*)&s_f[row * 40 + q4 * 8] = o;
        if (q4 == 3) s_mask[row] = v1.w;
    }
    // ---- stage others rows -> s_h rows 96,97 (t<64) ----
    if (t < 64) {
        const int r = t >> 5, seg = t & 31;
        const float* src = obs + (size_t)(b0 + r) * OBS_COLS + OTH_OFF + seg * 8;
        const float4 v0 = ((const float4*)src)[0];
        const float4 v1 = ((const float4*)src)[1];
        bf16x8 o;
        o[0]=(__bf16)v0.x; o[1]=(__bf16)v0.y; o[2]=(__bf16)v0.z; o[3]=(__bf16)v0.w;
        o[4]=(__bf16)v1.x; o[5]=(__bf16)v1.y; o[6]=(__bf16)v1.z; o[7]=(__bf16)v1.w;
        *(bf16x8*)&s_h[shx(96 + r, seg * 8)] = o;
    }
    // ---- zero garbage rows 98..127 of O input region ----
    {
        bf16x8 z;
        #pragma unroll
        for (int j = 0; j < 8; ++j) z[j] = (__bf16)0.0f;
        #pragma unroll
        for (int i = 0; i < 2; ++i) {
            const int u = i * 512 + t;
            if (u < 960) {
                const int row = 98 + (u >> 5), seg = u & 31;
                *(bf16x8*)&s_h[shx(row, seg * 8)] = z;
            }
        }
    }
    __syncthreads();

    f32x16 acc[2][2];
    f32x16 vzero;
    #pragma unroll
    for (int i = 0; i < 16; ++i) vzero[i] = 0.0f;

    // ========== O-L1: h1o = relu(oth @ oW1 + ob1), rows 96.. -> 64.. ==========
    {
        const bf16x8* Bg = (const bf16x8*)wp + S_OW1 * 512;
        f32x16 a1 = vzero;
        bf16x8 bc = Bg[ct * 64 + lane];
        bf16x8 bn = Bg[(8 + ct) * 64 + lane];
        #pragma unroll 4
        for (int kt = 0; kt < 16; ++kt) {
            const bf16x8 b2 = Bg[((((kt + 2) & 15)) * 8 + ct) * 64 + lane];
            const bf16x8 a = *(const bf16x8*)&s_h[shx(96 + lm, kt * 16 + lh * 8)];
            a1 = __builtin_amdgcn_mfma_f32_32x32x16_bf16(bc, a, a1, 0, 0, 0);
            bc = bn; bn = b2;
        }
        const float* bias = &ob1[ct * 32 + 4 * lh];
        #pragma unroll
        for (int g = 0; g < 4; ++g) {
            bf16x4 v;
            #pragma unroll
            for (int q = 0; q < 4; ++q)
                v[q] = (__bf16)fmaxf(a1[g * 4 + q] + bias[8 * g + q], 0.0f);
            *(bf16x4*)&s_h[((64 + lm) << 8) + ((((ct << 2) + g) ^ lm) << 3) + 4 * lh] = v;
        }
    }
    __syncthreads();

    // ========== O-L2: e = h1o @ oW2 + ob2 -> out(rows 0,1) + rows 96.. ==========
    {
        const bf16x8* Bg = (const bf16x8*)wp + S_OW2 * 512;
        f32x16 a1 = vzero;
        bf16x8 bc = Bg[ct * 64 + lane];
        bf16x8 bn = Bg[(8 + ct) * 64 + lane];
        #pragma unroll 4
        for (int kt = 0; kt < 16; ++kt) {
            const bf16x8 b2 = Bg[((((kt + 2) & 15)) * 8 + ct) * 64 + lane];
            const bf16x8 a = *(const bf16x8*)&s_h[shx(64 + lm, kt * 16 + lh * 8)];
            a1 = __builtin_amdgcn_mfma_f32_32x32x16_bf16(bc, a, a1, 0, 0, 0);
            bc = bn; bn = b2;
        }
        const float* bias = &ob2[ct * 32 + 4 * lh];
        #pragma unroll
        for (int g = 0; g < 4; ++g) {
            float4 fv; bf16x4 v;
            float* fp = &fv.x;
            #pragma unroll
            for (int q = 0; q < 4; ++q) {
                const float f2 = a1[g * 4 + q] + bias[8 * g + q];
                fp[q] = f2; v[q] = (__bf16)f2;
            }
            if (lm < 2)
                *(float4*)&out[(size_t)(b0 + lm) * OUTC + ct * 32 + 4 * lh + 8 * g] = fv;
            *(bf16x4*)&s_h[((96 + lm) << 8) + ((((ct << 2) + g) ^ lm) << 3) + 4 * lh] = v;
        }
    }
    __syncthreads();

    // ========== O-L3: qk = e @ WQK + bqk -> s_qk ; qb -> s_qb ==========
    {
        const bf16x8* Bg = (const bf16x8*)wp + S_WQK * 512;
        f32x16 a1 = vzero;
        bf16x8 bc = Bg[ct * 64 + lane];
        bf16x8 bn = Bg[(8 + ct) * 64 + lane];
        #pragma unroll 4
        for (int kt = 0; kt < 16; ++kt) {
            const bf16x8 b2 = Bg[((((kt + 2) & 15)) * 8 + ct) * 64 + lane];
            const bf16x8 a = *(const bf16x8*)&s_h[shx(96 + lm, kt * 16 + lh * 8)];
            a1 = __builtin_amdgcn_mfma_f32_32x32x16_bf16(bc, a, a1, 0, 0, 0);
            bc = bn; bn = b2;
        }
        if (lm < 2) {
            const int h = ct >> 1;
            #pragma unroll
            for (int g = 0; g < 4; ++g)
                #pragma unroll
                for (int q = 0; q < 4; ++q) {
                    const int n = ct * 32 + 4 * lh + 8 * g + q;
                    const int d = (ct & 1) * 32 + 4 * lh + 8 * g + q;
                    s_qk[(lm * 4 + h) * 64 + d] = a1[g * 4 + q] + fold[n];
                }
        }
        // qb[r][h] = e_r . wqb[:,h] + qbc[h]  (wave wv = r*4+h)
        {
            const int r = wv >> 2, h = wv & 3;
            float pq = 0.0f;
            #pragma unroll
            for (int i = 0; i < 4; ++i) {
                const int c = lane + i * 64;
                const float ec = (float)s_h[shx(96 + r, c)];
                pq += ec * fold[256 + c * 4 + h];
            }
            #pragma unroll
            for (int off = 32; off > 0; off >>= 1) pq += __shfl_xor(pq, off, 64);
            if (lane == 0) s_qb[wv] = pq + fold[1280 + h];
        }
    }
    __syncthreads();

    // ========== GEMM1: h1 = relu(feats @ W1p + b1), K=32 ==========
    {
        #pragma unroll
        for (int r = 0; r < 2; ++r)
            #pragma unroll
            for (int c = 0; c < 2; ++c) acc[r][c] = vzero;
        #pragma unroll
        for (int kt = 0; kt < 2; ++kt) {
            const bf16x8 a0 = *(const bf16x8*)&s_f[row0 * 40 + kt * 16 + lh * 8];
            const bf16x8 a1 = *(const bf16x8*)&s_f[row1 * 40 + kt * 16 + lh * 8];
            acc[0][0] = __builtin_amdgcn_mfma_f32_32x32x16_bf16(b1[kt][0], a0, acc[0][0], 0, 0, 0);
            acc[0][1] = __builtin_amdgcn_mfma_f32_32x32x16_bf16(b1[kt][1], a0, acc[0][1], 0, 0, 0);
            acc[1][0] = __builtin_amdgcn_mfma_f32_32x32x16_bf16(b1[kt][0], a1, acc[1][0], 0, 0, 0);
            acc[1][1] = __builtin_amdgcn_mfma_f32_32x32x16_bf16(b1[kt][1], a1, acc[1][1], 0, 0, 0);
        }
        #pragma unroll
        for (int r = 0; r < 2; ++r) {
            const int row = r ? row1 : row0;
            #pragma unroll
            for (int c = 0; c < 2; ++c) {
                const float* bias = &pb1[(ct0 + c) * 32 + 4 * lh];
                #pragma unroll
                for (int g = 0; g < 4; ++g) {
                    bf16x4 v;
                    #pragma unroll
                    for (int q = 0; q < 4; ++q)
                        v[q] = (__bf16)fmaxf(acc[r][c][g * 4 + q] + bias[8 * g + q], 0.0f);
                    *(bf16x4*)&s_h[(row << 8) + (((((ct0 + c) << 2) + g) ^ lm) << 3) + 4 * lh] = v;
                }
            }
        }
    }
    __syncthreads();

    // ========== GEMM2: h2 = relu(h1 @ W2 + b2), K=256 ==========
    {
        const bf16x8* Bg = (const bf16x8*)wp + S_PW2 * 512;
        #pragma unroll
        for (int r = 0; r < 2; ++r)
            #pragma unroll
            for (int c = 0; c < 2; ++c) acc[r][c] = vzero;
        bf16x8 bc0 = Bg[(ct0 + 0) * 64 + lane];
        bf16x8 bc1 = Bg[(ct0 + 1) * 64 + lane];
        #pragma unroll 4
        for (int kt = 0; kt < 16; ++kt) {
            const int kn = (kt + 1) & 15;
            const bf16x8 bn0 = Bg[(kn * 8 + ct0 + 0) * 64 + lane];
            const bf16x8 bn1 = Bg[(kn * 8 + ct0 + 1) * 64 + lane];
            const bf16x8 a0 = *(const bf16x8*)&s_h[(row0 << 8) + (((2 * kt + lh) ^ lm) << 3)];
            const bf16x8 a1 = *(const bf16x8*)&s_h[(row1 << 8) + (((2 * kt + lh) ^ lm) << 3)];
            acc[0][0] = __builtin_amdgcn_mfma_f32_32x32x16_bf16(bc0, a0, acc[0][0], 0, 0, 0);
            acc[0][1] = __builtin_amdgcn_mfma_f32_32x32x16_bf16(bc1, a0, acc[0][1], 0, 0, 0);
            acc[1][0] = __builtin_amdgcn_mfma_f32_32x32x16_bf16(bc0, a1, acc[1][0], 0, 0, 0);
            acc[1][1] = __builtin_amdgcn_mfma_f32_32x32x16_bf16(bc1, a1, acc[1][1], 0, 0, 0);
            bc0 = bn0; bc1 = bn1;
        }
        __syncthreads();
        #pragma unroll
        for (int r = 0; r < 2; ++r) {
            const int row = r ? row1 : row0;
            #pragma unroll
            for (int c = 0; c < 2; ++c) {
                const float* bias = &pb2[(ct0 + c) * 32 + 4 * lh];
                #pragma unroll
                for (int g = 0; g < 4; ++g) {
                    bf16x4 v;
                    #pragma unroll
                    for (int q = 0; q < 4; ++q)
                        v[q] = (__bf16)fmaxf(acc[r][c][g * 4 + q] + bias[8 * g + q], 0.0f);
                    *(bf16x4*)&s_h[(row << 8) + (((((ct0 + c) << 2) + g) ^ lm) << 3) + 4 * lh] = v;
                }
            }
        }
    }
    __syncthreads();

    // ========== GEMM3: E = (h2 @ W3 + b3) * mask, K=256 ==========
    {
        const bf16x8* Bg = (const bf16x8*)wp + S_PW3 * 512;
        #pragma unroll
        for (int r = 0; r < 2; ++r)
            #pragma unroll
            for (int c = 0; c < 2; ++c) acc[r][c] = vzero;
        bf16x8 bc0 = Bg[(ct0 + 0) * 64 + lane];
        bf16x8 bc1 = Bg[(ct0 + 1) * 64 + lane];
        #pragma unroll 4
        for (int kt = 0; kt < 16; ++kt) {
            const int kn = (kt + 1) & 15;
            const bf16x8 bn0 = Bg[(kn * 8 + ct0 + 0) * 64 + lane];
            const bf16x8 bn1 = Bg[(kn * 8 + ct0 + 1) * 64 + lane];
            const bf16x8 a0 = *(const bf16x8*)&s_h[(row0 << 8) + (((2 * kt + lh) ^ lm) << 3)];
            const bf16x8 a1 = *(const bf16x8*)&s_h[(row1 << 8) + (((2 * kt + lh) ^ lm) << 3)];
            acc[0][0] = __builtin_amdgcn_mfma_f32_32x32x16_bf16(bc0, a0, acc[0][0], 0, 0, 0);
            acc[0][1] = __builtin_amdgcn_mfma_f32_32x32x16_bf16(bc1, a0, acc[0][1], 0, 0, 0);
            acc[1][0] = __builtin_amdgcn_mfma_f32_32x32x16_bf16(bc0, a1, acc[1][0], 0, 0, 0);
            acc[1][1] = __builtin_amdgcn_mfma_f32_32x32x16_bf16(bc1, a1, acc[1][1], 0, 0, 0);
            bc0 = bn0; bc1 = bn1;
        }
        __syncthreads();
        #pragma unroll
        for (int r = 0; r < 2; ++r) {
            const int row = r ? row1 : row0;
            const float mk = s_mask[row];
            #pragma unroll
            for (int c = 0; c < 2; ++c) {
                const float* bias = &pb3[(ct0 + c) * 32 + 4 * lh];
                #pragma unroll
                for (int g = 0; g < 4; ++g) {
                    bf16x4 v;
                    #pragma unroll
                    for (int q = 0; q < 4; ++q)
                        v[q] = (__bf16)((acc[r][c][g * 4 + q] + bias[8 * g + q]) * mk);
                    *(bf16x4*)&s_h[(row << 8) + (((((ct0 + c) << 2) + g) ^ lm) << 3) + 4 * lh] = v;
                }
            }
        }
    }
    __syncthreads();

    // ---- Phase B: logits + softmax (wave = one (r,h) unit; lane = object) ----
    {
        const int r = wv >> 2, h = wv & 3;
        const float qb = s_qb[wv];
        const int erow = r * 64 + lane;
        float dot = 0.0f;
        #pragma unroll
        for (int d8 = 0; d8 < 8; ++d8) {
            const bf16x8 ev = *(const bf16x8*)&s_h[(erow << 8) + ((((h << 3) + d8) ^ (erow & 31)) << 3)];
            const float* kv = &s_qk[(r * 4 + h) * 64 + d8 * 8];
            #pragma unroll
            for (int j = 0; j < 8; ++j) dot += (float)ev[j] * kv[j];
        }
        const float mk = s_mask[erow];
        float logit = (dot + qb) * 0.0625f;
        if (mk == 0.0f) logit = -1.0e9f;
        float m = logit;
        #pragma unroll
        for (int off = 32; off > 0; off >>= 1) m = fmaxf(m, __shfl_xor(m, off, 64));
        const float ex = __expf(logit - m);
        float ssum = ex;
        #pragma unroll
        for (int off = 32; off > 0; off >>= 1) ssum += __shfl_xor(ssum, off, 64);
        const float am = (ex / ssum) * mk;
        s_am[(r * 4 + h) * 64 + lane] = am;
        float ams = am;
        #pragma unroll
        for (int off = 32; off > 0; off >>= 1) ams += __shfl_xor(ams, off, 64);
        if (lane == 0) s_amsum[r * 4 + h] = ams;
    }
    __syncthreads();

    // ---- Phase C: p[r][h][d] = sum_n am * E[n][h*64+d] -> s_p ----
    {
        const int r = t >> 8, h = (t >> 6) & 3, d = t & 63;
        const float* amr = &s_am[(r * 4 + h) * 64];
        const int blkbase = (h << 3) + (d >> 3);
        const int doff = d & 7;
        float a = 0.0f;
        #pragma unroll 16
        for (int n = 0; n < 64; ++n) {
            const int row = r * 64 + n;
            a += amr[n] * (float)s_h[(row << 8) + (((blkbase ^ (row & 31)) << 3) | doff)];
        }
        s_p[(r * 4 + h) * 64 + d] = a;
    }
    __syncthreads();

    // ---- Phase D: out_emb = p @ Wv + amsum * bv ----
    {
        const int r = t >> 8, h = (t >> 6) & 3, e = t & 63;
        float a = s_amsum[r * 4 + h] * bv[h * 64 + e];
        const float* pr  = &s_p[(r * 4 + h) * 64];
        const float* wvp = Wv + (size_t)h * 64 * 64 + e;
        #pragma unroll 16
        for (int d = 0; d < 64; ++d)
            a += pr[d] * wvp[d * 64];
        out[(size_t)(b0 + r) * OUTC + EMB + h * 64 + e] = a;
    }
}

extern "C" void kernel_launch(void* const* d_in, const int* in_sizes, int n_in,
                              void* d_out, int out_size, void* d_ws, size_t ws_size,
                              hipStream_t stream)
{
    const float* obs = (const float*)d_in[0];
    const float* oW1 = (const float*)d_in[1];
    const float* ob1 = (const float*)d_in[2];
    const float* oW2 = (const float*)d_in[3];
    const float* ob2 = (const float*)d_in[4];
    const float* pW1 = (const float*)d_in[5];
    const float* pb1 = (const float*)d_in[6];
    const float* pW2 = (const float*)d_in[7];
    const float* pb2 = (const float*)d_in[8];
    const float* pW3 = (const float*)d_in[9];
    const float* pb3 = (const float*)d_in[10];
    const float* Wq  = (const float*)d_in[11];
    const float* bq  = (const float*)d_in[12];
    const float* Wk  = (const float*)d_in[13];
    const float* bk  = (const float*)d_in[14];
    const float* Wv  = (const float*)d_in[15];
    const float* bv  = (const float*)d_in[16];
    float*  out  = (float*)d_out;
    float*  fold = (float*)d_ws;
    __bf16* wp   = (__bf16*)((char*)d_ws + FOLD_BYTES);

    k_prep<<<83, 512, 0, stream>>>(pW1, pW2, pW3, oW1, oW2, Wq, Wk, bq, bk,
                                   fold, wp);
    k_obj<<<BATCH / 2, 512, 0, stream>>>(obs, wp, fold, ob1, ob2,
                                         pb1, pb2, pb3, bv, Wv, out);
}

// Round 8
// 240.667 us; speedup vs baseline: 1.1234x; 1.1234x over previous
//
#include <hip/hip_runtime.h>

#define BATCH      4096
#define OBS_COLS   2304
#define OTH_OFF    2048
#define EMB        256
#define OUTC       512

// ws layout: qk (4096x256 f32) | qb (4096x4 f32) | packed pW slices (34 x 8KB)
#define QK_BYTES   (4096u * 256u * 4u)
#define QB_BYTES   (4096u * 4u * 4u)

typedef __bf16 bf16x8 __attribute__((ext_vector_type(8)));
typedef __bf16 bf16x4 __attribute__((ext_vector_type(4)));
typedef float  f32x16 __attribute__((ext_vector_type(16)));

// Slice bases (units of 512 bf16x8 = one 16x256 K-step slice) within wp
#define S_PW1  0
#define S_PW2  2
#define S_PW3  18
#define N_SLICE 34

// Swizzled element index into a [rows][256] bf16 LDS tile.
__device__ __forceinline__ int shx(int row, int col) {
    return (row << 8) + ((((col >> 3) ^ (row & 31)) << 3) | (col & 7));
}

// ---------------------------------------------------------------------------
// k_oth: 128 WGs x 512 thr (identical to R6 — passed at 229.6 total).
//  - WGs 0..33 pack one pW slice into wp (for k_obj).
//  - others MLP (M=32/WG), B-fragments direct from fp32 weights.
//  - L3 computes q, then qk = Wk.q (4 MFMAs/wave) and qb = q.bk -> ws.
// ---------------------------------------------------------------------------
__global__ __launch_bounds__(512, 2) void k_oth(
    const float* __restrict__ obs,
    const float* __restrict__ oW1, const float* __restrict__ ob1,
    const float* __restrict__ oW2, const float* __restrict__ ob2,
    const float* __restrict__ Wq,  const float* __restrict__ bq,
    const float* __restrict__ Wk,  const float* __restrict__ bk,
    const float* __restrict__ pW1, const float* __restrict__ pW2,
    const float* __restrict__ pW3,
    float* __restrict__ out, float* __restrict__ qkg,
    float* __restrict__ qbg, __bf16* __restrict__ wp)
{
    __shared__ __align__(16) __bf16 s_a[32 * 256];   // 16 KB
    __shared__ __align__(16) __bf16 s_h[32 * 256];   // 16 KB
    __shared__ __align__(16) __bf16 s_q[32 * 256];   // 16 KB
    __shared__ float s_qb[32 * 4];

    const int t  = threadIdx.x;
    const int b0 = blockIdx.x * 32;
    const int wv = t >> 6, lane = t & 63;
    const int lm = lane & 31, lh = lane >> 5;
    const int ct = wv;                 // col tile 0..7

    // ---- pack pW slices for k_obj (WGs 0..33) ----
    if (blockIdx.x < N_SLICE) {
        const int s = blockIdx.x;
        int kt; const float* W; int isW1 = 0;
        if      (s < S_PW2) { kt = s;         W = pW1; isW1 = 1; }
        else if (s < S_PW3) { kt = s - S_PW2; W = pW2; }
        else                { kt = s - S_PW3; W = pW3; }
        const int kbase = kt * 16 + lh * 8;
        const int n     = (t >> 6) * 32 + lm;   // ct*32 + lm
        bf16x8 v;
        #pragma unroll
        for (int j = 0; j < 8; ++j) {
            const int k = kbase + j;
            const float f = (isW1 && k >= 31) ? 0.0f : W[k * 256 + n];
            v[j] = (__bf16)f;
        }
        ((bf16x8*)wp)[(size_t)s * 512 + t] = v;
    }

    // ---- stage 32 rows x 256 cols (fp32 -> bf16, swizzled) ----
    #pragma unroll
    for (int i = 0; i < 2; ++i) {
        const int c = i * 512 + t;
        const int row = c >> 5, seg = c & 31;
        const float* src = obs + (size_t)(b0 + row) * OBS_COLS + OTH_OFF + seg * 8;
        const float4 v0 = ((const float4*)src)[0];
        const float4 v1 = ((const float4*)src)[1];
        bf16x8 o;
        o[0]=(__bf16)v0.x; o[1]=(__bf16)v0.y; o[2]=(__bf16)v0.z; o[3]=(__bf16)v0.w;
        o[4]=(__bf16)v1.x; o[5]=(__bf16)v1.y; o[6]=(__bf16)v1.z; o[7]=(__bf16)v1.w;
        *(bf16x8*)&s_a[shx(row, seg * 8)] = o;
    }
    if (t < 128) s_qb[t] = 0.0f;
    __syncthreads();

    f32x16 acc;
    f32x16 vzero;
    #pragma unroll
    for (int i = 0; i < 16; ++i) vzero[i] = 0.0f;

    // ---- L1: h = relu(A @ oW1 + ob1); B direct from fp32, depth-1 rot ----
    {
        const float* Wl = oW1 + (size_t)(lh * 8) * 256 + ct * 32 + lm;
        acc = vzero;
        float f[8];
        #pragma unroll
        for (int j = 0; j < 8; ++j) f[j] = Wl[j * 256];
        #pragma unroll 4
        for (int kt = 0; kt < 16; ++kt) {
            float fn[8];
            const int kn = (kt + 1) & 15;
            #pragma unroll
            for (int j = 0; j < 8; ++j) fn[j] = Wl[(kn * 16 + j) * 256];
            bf16x8 b;
            #pragma unroll
            for (int j = 0; j < 8; ++j) b[j] = (__bf16)f[j];
            const bf16x8 a = *(const bf16x8*)&s_a[shx(lm, kt * 16 + lh * 8)];
            acc = __builtin_amdgcn_mfma_f32_32x32x16_bf16(b, a, acc, 0, 0, 0);
            #pragma unroll
            for (int j = 0; j < 8; ++j) f[j] = fn[j];
        }
        const float* bias = &ob1[ct * 32 + 4 * lh];
        #pragma unroll
        for (int g = 0; g < 4; ++g) {
            bf16x4 v;
            #pragma unroll
            for (int q = 0; q < 4; ++q)
                v[q] = (__bf16)fmaxf(acc[g * 4 + q] + bias[8 * g + q], 0.0f);
            *(bf16x4*)&s_h[(lm << 8) + ((((ct << 2) + g) ^ lm) << 3) + 4 * lh] = v;
        }
    }
    __syncthreads();

    // ---- L2: e = s_h @ oW2 + ob2 -> out (fp32) + s_a (bf16) ----
    {
        const float* Wl = oW2 + (size_t)(lh * 8) * 256 + ct * 32 + lm;
        acc = vzero;
        float f[8];
        #pragma unroll
        for (int j = 0; j < 8; ++j) f[j] = Wl[j * 256];
        #pragma unroll 4
        for (int kt = 0; kt < 16; ++kt) {
            float fn[8];
            const int kn = (kt + 1) & 15;
            #pragma unroll
            for (int j = 0; j < 8; ++j) fn[j] = Wl[(kn * 16 + j) * 256];
            bf16x8 b;
            #pragma unroll
            for (int j = 0; j < 8; ++j) b[j] = (__bf16)f[j];
            const bf16x8 a = *(const bf16x8*)&s_h[shx(lm, kt * 16 + lh * 8)];
            acc = __builtin_amdgcn_mfma_f32_32x32x16_bf16(b, a, acc, 0, 0, 0);
            #pragma unroll
            for (int j = 0; j < 8; ++j) f[j] = fn[j];
        }
        const float* bias = &ob2[ct * 32 + 4 * lh];
        float* dstg = &out[(size_t)(b0 + lm) * OUTC + ct * 32 + 4 * lh];
        #pragma unroll
        for (int g = 0; g < 4; ++g) {
            float4 fv; bf16x4 v;
            float* fp = &fv.x;
            #pragma unroll
            for (int q = 0; q < 4; ++q) {
                const float f2 = acc[g * 4 + q] + bias[8 * g + q];
                fp[q] = f2; v[q] = (__bf16)f2;
            }
            *(float4*)&dstg[8 * g] = fv;
            *(bf16x4*)&s_a[(lm << 8) + ((((ct << 2) + g) ^ lm) << 3) + 4 * lh] = v;
        }
    }
    __syncthreads();

    // ---- L3: q = s_a @ Wq + bq -> s_q (bf16) ; qb partial -> s_qb ----
    {
        const float* Wl = Wq + (size_t)(lh * 8) * 256 + ct * 32 + lm;
        acc = vzero;
        float f[8];
        #pragma unroll
        for (int j = 0; j < 8; ++j) f[j] = Wl[j * 256];
        #pragma unroll 4
        for (int kt = 0; kt < 16; ++kt) {
            float fn[8];
            const int kn = (kt + 1) & 15;
            #pragma unroll
            for (int j = 0; j < 8; ++j) fn[j] = Wl[(kn * 16 + j) * 256];
            bf16x8 b;
            #pragma unroll
            for (int j = 0; j < 8; ++j) b[j] = (__bf16)f[j];
            const bf16x8 a = *(const bf16x8*)&s_a[shx(lm, kt * 16 + lh * 8)];
            acc = __builtin_amdgcn_mfma_f32_32x32x16_bf16(b, a, acc, 0, 0, 0);
            #pragma unroll
            for (int j = 0; j < 8; ++j) f[j] = fn[j];
        }
        const int hh = ct >> 1;    // head this col-tile belongs to
        const float* bias = &bq[ct * 32 + 4 * lh];
        const float* bkp  = &bk[ct * 32 + 4 * lh];
        float part = 0.0f;
        #pragma unroll
        for (int g = 0; g < 4; ++g) {
            bf16x4 v;
            #pragma unroll
            for (int q = 0; q < 4; ++q) {
                const float f2 = acc[g * 4 + q] + bias[8 * g + q];
                part += f2 * bkp[8 * g + q];
                v[q] = (__bf16)f2;
            }
            *(bf16x4*)&s_q[(lm << 8) + ((((ct << 2) + g) ^ lm) << 3) + 4 * lh] = v;
        }
        part += __shfl_xor(part, 32, 64);
        if (lane < 32) atomicAdd(&s_qb[lm * 4 + hh], part);
    }
    __syncthreads();

    // ---- qb out ----
    if (t < 128) qbg[(size_t)(b0 + (t >> 2)) * 4 + (t & 3)] = s_qb[t];

    // ---- qk[row][h*64+d] = sum_e Wk[h][d][e]*q[row][h*64+e] via MFMA ----
    {
        const int h = wv >> 1, c2 = wv & 1;   // 8 waves = 4 heads x 2 col-tiles
        acc = vzero;
        #pragma unroll
        for (int kt = 0; kt < 4; ++kt) {
            const float* wk = Wk + ((size_t)(h * 64 + c2 * 32 + lm) * 64 + kt * 16 + lh * 8);
            const float4 w0 = *(const float4*)wk;
            const float4 w1 = *(const float4*)(wk + 4);
            bf16x8 b;
            b[0]=(__bf16)w0.x; b[1]=(__bf16)w0.y; b[2]=(__bf16)w0.z; b[3]=(__bf16)w0.w;
            b[4]=(__bf16)w1.x; b[5]=(__bf16)w1.y; b[6]=(__bf16)w1.z; b[7]=(__bf16)w1.w;
            const bf16x8 a = *(const bf16x8*)&s_q[shx(lm, h * 64 + kt * 16 + lh * 8)];
            acc = __builtin_amdgcn_mfma_f32_32x32x16_bf16(b, a, acc, 0, 0, 0);
        }
        float* dstg = &qkg[(size_t)(b0 + lm) * 256 + h * 64 + c2 * 32 + 4 * lh];
        #pragma unroll
        for (int g = 0; g < 4; ++g) {
            float4 fv;
            float* fp = &fv.x;
            #pragma unroll
            for (int q = 0; q < 4; ++q) fp[q] = acc[g * 4 + q];
            *(float4*)&dstg[8 * g] = fv;
        }
    }
}

// ---------------------------------------------------------------------------
// k_obj: M=64 (1 batch row)/WG, 256 thr (4 waves), 4096 WGs, 39.2 KB LDS
// -> 4 WGs/CU (16 waves). Wave tile 64x64 (rows lm,lm+32 x ct0..ct0+1).
// acc 64 regs; depth-1 B rotation. Phases C/D vectorized (8-lane units,
// bf16x8/float4 reads + xor-shuffle reduction).
// ---------------------------------------------------------------------------
__global__ __launch_bounds__(256, 4) void k_obj(
    const float* __restrict__ obs,  const __bf16* __restrict__ wp,
    const float* __restrict__ pb1,  const float* __restrict__ pb2,
    const float* __restrict__ pb3,  const float* __restrict__ qkg,
    const float* __restrict__ qbg,  const float* __restrict__ bv,
    const float* __restrict__ Wv,   float* __restrict__ out)
{
    __shared__ __align__(16) __bf16 s_h[64 * 256];   // 32768 B (swizzled)
    __shared__ __align__(16) char s_fp[64 * 32 * 2]; // 4096 B: feats, later p
    __bf16* s_f = (__bf16*)s_fp;
    float*  s_p = (float*)s_fp;                      // 4*64 f32 = 1024 B
    __shared__ float s_mask[64];
    __shared__ float s_qk[4 * 64];
    __shared__ float s_am[4 * 64];
    __shared__ float s_amsum[4];
    __shared__ float s_qb[4];

    const int t  = threadIdx.x;
    const int b  = blockIdx.x;
    const int wv = t >> 6, lane = t & 63;
    const int lm = lane & 31, lh = lane >> 5;
    const int ct0 = wv * 2;            // col tiles ct0, ct0+1
    const int row0 = lm;
    const int row1 = lm + 32;

    // GEMM1 B-fragments: independent of staging, issue early
    bf16x8 b1[2][2];
    {
        const bf16x8* Bg = (const bf16x8*)wp + S_PW1 * 512;
        #pragma unroll
        for (int kt = 0; kt < 2; ++kt)
            #pragma unroll
            for (int c = 0; c < 2; ++c)
                b1[kt][c] = Bg[(kt * 8 + ct0 + c) * 64 + lane];
    }

    // ---- stage 64 object rows x 32 feats as bf16 (stride 32) + mask ----
    {
        const int row = t >> 2, q4 = t & 3;
        const float* src = obs + (size_t)b * OBS_COLS + row * 32 + q4 * 8;
        const float4 v0 = ((const float4*)src)[0];
        const float4 v1 = ((const float4*)src)[1];
        bf16x8 o;
        o[0]=(__bf16)v0.x; o[1]=(__bf16)v0.y; o[2]=(__bf16)v0.z; o[3]=(__bf16)v0.w;
        o[4]=(__bf16)v1.x; o[5]=(__bf16)v1.y; o[6]=(__bf16)v1.z; o[7]=(__bf16)v1.w;
        *(bf16x8*)&s_f[row * 32 + q4 * 8] = o;
        if (q4 == 3) s_mask[row] = v1.w;
    }
    // ---- stage qk (64 float4 = 256 f32) and qb ----
    if (t < 64) ((float4*)s_qk)[t] = ((const float4*)(qkg + (size_t)b * 256))[t];
    if (t >= 64 && t < 68) s_qb[t - 64] = qbg[(size_t)b * 4 + (t - 64)];
    __syncthreads();

    f32x16 acc[2][2];
    f32x16 vzero;
    #pragma unroll
    for (int i = 0; i < 16; ++i) vzero[i] = 0.0f;

    // ========== GEMM1: h1 = relu(feats @ W1p + b1), K=32 ==========
    {
        #pragma unroll
        for (int r = 0; r < 2; ++r)
            #pragma unroll
            for (int c = 0; c < 2; ++c) acc[r][c] = vzero;
        #pragma unroll
        for (int kt = 0; kt < 2; ++kt) {
            const bf16x8 a0 = *(const bf16x8*)&s_f[row0 * 32 + kt * 16 + lh * 8];
            const bf16x8 a1 = *(const bf16x8*)&s_f[row1 * 32 + kt * 16 + lh * 8];
            acc[0][0] = __builtin_amdgcn_mfma_f32_32x32x16_bf16(b1[kt][0], a0, acc[0][0], 0, 0, 0);
            acc[0][1] = __builtin_amdgcn_mfma_f32_32x32x16_bf16(b1[kt][1], a0, acc[0][1], 0, 0, 0);
            acc[1][0] = __builtin_amdgcn_mfma_f32_32x32x16_bf16(b1[kt][0], a1, acc[1][0], 0, 0, 0);
            acc[1][1] = __builtin_amdgcn_mfma_f32_32x32x16_bf16(b1[kt][1], a1, acc[1][1], 0, 0, 0);
        }
        #pragma unroll
        for (int r = 0; r < 2; ++r) {
            const int row = r ? row1 : row0;
            #pragma unroll
            for (int c = 0; c < 2; ++c) {
                const float* bias = &pb1[(ct0 + c) * 32 + 4 * lh];
                #pragma unroll
                for (int g = 0; g < 4; ++g) {
                    bf16x4 v;
                    #pragma unroll
                    for (int q = 0; q < 4; ++q)
                        v[q] = (__bf16)fmaxf(acc[r][c][g * 4 + q] + bias[8 * g + q], 0.0f);
                    *(bf16x4*)&s_h[(row << 8) + (((((ct0 + c) << 2) + g) ^ lm) << 3) + 4 * lh] = v;
                }
            }
        }
    }
    __syncthreads();

    // ========== GEMM2: h2 = relu(h1 @ W2 + b2), K=256 ==========
    {
        const bf16x8* Bg = (const bf16x8*)wp + S_PW2 * 512;
        #pragma unroll
        for (int r = 0; r < 2; ++r)
            #pragma unroll
            for (int c = 0; c < 2; ++c) acc[r][c] = vzero;
        bf16x8 bc0 = Bg[(ct0 + 0) * 64 + lane];
        bf16x8 bc1 = Bg[(ct0 + 1) * 64 + lane];
        #pragma unroll 4
        for (int kt = 0; kt < 16; ++kt) {
            const int kn = (kt + 1) & 15;
            const bf16x8 bn0 = Bg[(kn * 8 + ct0 + 0) * 64 + lane];
            const bf16x8 bn1 = Bg[(kn * 8 + ct0 + 1) * 64 + lane];
            const bf16x8 a0 = *(const bf16x8*)&s_h[(row0 << 8) + (((2 * kt + lh) ^ lm) << 3)];
            const bf16x8 a1 = *(const bf16x8*)&s_h[(row1 << 8) + (((2 * kt + lh) ^ lm) << 3)];
            acc[0][0] = __builtin_amdgcn_mfma_f32_32x32x16_bf16(bc0, a0, acc[0][0], 0, 0, 0);
            acc[0][1] = __builtin_amdgcn_mfma_f32_32x32x16_bf16(bc1, a0, acc[0][1], 0, 0, 0);
            acc[1][0] = __builtin_amdgcn_mfma_f32_32x32x16_bf16(bc0, a1, acc[1][0], 0, 0, 0);
            acc[1][1] = __builtin_amdgcn_mfma_f32_32x32x16_bf16(bc1, a1, acc[1][1], 0, 0, 0);
            bc0 = bn0; bc1 = bn1;
        }
        __syncthreads();   // all reads of h1 done before in-place overwrite
        #pragma unroll
        for (int r = 0; r < 2; ++r) {
            const int row = r ? row1 : row0;
            #pragma unroll
            for (int c = 0; c < 2; ++c) {
                const float* bias = &pb2[(ct0 + c) * 32 + 4 * lh];
                #pragma unroll
                for (int g = 0; g < 4; ++g) {
                    bf16x4 v;
                    #pragma unroll
                    for (int q = 0; q < 4; ++q)
                        v[q] = (__bf16)fmaxf(acc[r][c][g * 4 + q] + bias[8 * g + q], 0.0f);
                    *(bf16x4*)&s_h[(row << 8) + (((((ct0 + c) << 2) + g) ^ lm) << 3) + 4 * lh] = v;
                }
            }
        }
    }
    __syncthreads();

    // ========== GEMM3: E = (h2 @ W3 + b3) * mask, K=256 ==========
    {
        const bf16x8* Bg = (const bf16x8*)wp + S_PW3 * 512;
        #pragma unroll
        for (int r = 0; r < 2; ++r)
            #pragma unroll
            for (int c = 0; c < 2; ++c) acc[r][c] = vzero;
        bf16x8 bc0 = Bg[(ct0 + 0) * 64 + lane];
        bf16x8 bc1 = Bg[(ct0 + 1) * 64 + lane];
        #pragma unroll 4
        for (int kt = 0; kt < 16; ++kt) {
            const int kn = (kt + 1) & 15;
            const bf16x8 bn0 = Bg[(kn * 8 + ct0 + 0) * 64 + lane];
            const bf16x8 bn1 = Bg[(kn * 8 + ct0 + 1) * 64 + lane];
            const bf16x8 a0 = *(const bf16x8*)&s_h[(row0 << 8) + (((2 * kt + lh) ^ lm) << 3)];
            const bf16x8 a1 = *(const bf16x8*)&s_h[(row1 << 8) + (((2 * kt + lh) ^ lm) << 3)];
            acc[0][0] = __builtin_amdgcn_mfma_f32_32x32x16_bf16(bc0, a0, acc[0][0], 0, 0, 0);
            acc[0][1] = __builtin_amdgcn_mfma_f32_32x32x16_bf16(bc1, a0, acc[0][1], 0, 0, 0);
            acc[1][0] = __builtin_amdgcn_mfma_f32_32x32x16_bf16(bc0, a1, acc[1][0], 0, 0, 0);
            acc[1][1] = __builtin_amdgcn_mfma_f32_32x32x16_bf16(bc1, a1, acc[1][1], 0, 0, 0);
            bc0 = bn0; bc1 = bn1;
        }
        __syncthreads();
        #pragma unroll
        for (int r = 0; r < 2; ++r) {
            const int row = r ? row1 : row0;
            const float mk = s_mask[row];
            #pragma unroll
            for (int c = 0; c < 2; ++c) {
                const float* bias = &pb3[(ct0 + c) * 32 + 4 * lh];
                #pragma unroll
                for (int g = 0; g < 4; ++g) {
                    bf16x4 v;
                    #pragma unroll
                    for (int q = 0; q < 4; ++q)
                        v[q] = (__bf16)((acc[r][c][g * 4 + q] + bias[8 * g + q]) * mk);
                    *(bf16x4*)&s_h[(row << 8) + (((((ct0 + c) << 2) + g) ^ lm) << 3) + 4 * lh] = v;
                }
            }
        }
    }
    __syncthreads();

    // ---- Phase B: logits + softmax (wave = head h; lane = object n) ----
    {
        const int h = wv;
        const float qb = s_qb[h];
        float dot = 0.0f;
        #pragma unroll
        for (int d8 = 0; d8 < 8; ++d8) {
            const bf16x8 ev = *(const bf16x8*)&s_h[(lane << 8) + ((((h << 3) + d8) ^ (lane & 31)) << 3)];
            const float* kv = &s_qk[h * 64 + d8 * 8];
            #pragma unroll
            for (int j = 0; j < 8; ++j) dot += (float)ev[j] * kv[j];
        }
        const float mk = s_mask[lane];
        float logit = (dot + qb) * 0.0625f;
        if (mk == 0.0f) logit = -1.0e9f;
        float m = logit;
        #pragma unroll
        for (int off = 32; off > 0; off >>= 1) m = fmaxf(m, __shfl_xor(m, off, 64));
        const float ex = __expf(logit - m);
        float ssum = ex;
        #pragma unroll
        for (int off = 32; off > 0; off >>= 1) ssum += __shfl_xor(ssum, off, 64);
        const float am = (ex / ssum) * mk;
        s_am[h * 64 + lane] = am;
        float ams = am;
        #pragma unroll
        for (int off = 32; off > 0; off >>= 1) ams += __shfl_xor(ams, off, 64);
        if (lane == 0) s_amsum[h] = ams;
    }
    __syncthreads();

    // ---- Phase C: p[h][d] = sum_n am[n]*E[n][h*64+d] -> s_p ----
    // 8-lane units: h=wv, dblk=lane>>3 covers d=dblk*8..+7; lane j=lane&7
    // handles n = j*8..j*8+7 with bf16x8 reads; xor-shuffle reduce over j.
    {
        const int h = wv, dblk = lane >> 3, j = lane & 7;
        const int blk = (h << 3) + dblk;
        float a[8];
        #pragma unroll
        for (int dd = 0; dd < 8; ++dd) a[dd] = 0.0f;
        #pragma unroll
        for (int nn = 0; nn < 8; ++nn) {
            const int n = j * 8 + nn;
            const bf16x8 ev = *(const bf16x8*)&s_h[(n << 8) + ((blk ^ (n & 31)) << 3)];
            const float amv = s_am[h * 64 + n];
            #pragma unroll
            for (int dd = 0; dd < 8; ++dd) a[dd] += amv * (float)ev[dd];
        }
        #pragma unroll
        for (int off = 1; off <= 4; off <<= 1)
            #pragma unroll
            for (int dd = 0; dd < 8; ++dd) a[dd] += __shfl_xor(a[dd], off, 64);
        // lane j writes element d = dblk*8 + j (select a[j] via cndmask tree)
        const float s01 = (j & 1) ? a[1] : a[0];
        const float s23 = (j & 1) ? a[3] : a[2];
        const float s45 = (j & 1) ? a[5] : a[4];
        const float s67 = (j & 1) ? a[7] : a[6];
        const float t03 = (j & 2) ? s23 : s01;
        const float t47 = (j & 2) ? s67 : s45;
        const float val = (j & 4) ? t47 : t03;
        s_p[h * 64 + dblk * 8 + j] = val;
    }
    __syncthreads();

    // ---- Phase D: out_emb[h][e] = sum_d p[d]*Wv[h][d][e] + amsum*bv ----
    // units: h=wv, eblk=lane>>3 covers e=eblk*8..+7; lane j handles d=j*8..+7.
    {
        const int h = wv, eblk = lane >> 3, j = lane & 7;
        const float4 p0 = *(const float4*)&s_p[h * 64 + j * 8];
        const float4 p1 = *(const float4*)&s_p[h * 64 + j * 8 + 4];
        float pd[8] = {p0.x, p0.y, p0.z, p0.w, p1.x, p1.y, p1.z, p1.w};
        float a[8];
        #pragma unroll
        for (int ee = 0; ee < 8; ++ee) a[ee] = 0.0f;
        const float* wvb = Wv + (size_t)h * 4096 + eblk * 8;
        #pragma unroll
        for (int dd = 0; dd < 8; ++dd) {
            const int d = j * 8 + dd;
            const float4 w0 = *(const float4*)&wvb[d * 64];
            const float4 w1 = *(const float4*)&wvb[d * 64 + 4];
            a[0] += pd[dd] * w0.x; a[1] += pd[dd] * w0.y;
            a[2] += pd[dd] * w0.z; a[3] += pd[dd] * w0.w;
            a[4] += pd[dd] * w1.x; a[5] += pd[dd] * w1.y;
            a[6] += pd[dd] * w1.z; a[7] += pd[dd] * w1.w;
        }
        #pragma unroll
        for (int off = 1; off <= 4; off <<= 1)
            #pragma unroll
            for (int ee = 0; ee < 8; ++ee) a[ee] += __shfl_xor(a[ee], off, 64);
        const float s01 = (j & 1) ? a[1] : a[0];
        const float s23 = (j & 1) ? a[3] : a[2];
        const float s45 = (j & 1) ? a[5] : a[4];
        const float s67 = (j & 1) ? a[7] : a[6];
        const float t03 = (j & 2) ? s23 : s01;
        const float t47 = (j & 2) ? s67 : s45;
        float val = (j & 4) ? t47 : t03;
        val += s_amsum[h] * bv[h * 64 + lane];   // e == lane
        out[(size_t)b * OUTC + EMB + h * 64 + lane] = val;
    }
}

extern "C" void kernel_launch(void* const* d_in, const int* in_sizes, int n_in,
                              void* d_out, int out_size, void* d_ws, size_t ws_size,
                              hipStream_t stream)
{
    const float* obs = (const float*)d_in[0];
    const float* oW1 = (const float*)d_in[1];
    const float* ob1 = (const float*)d_in[2];
    const float* oW2 = (const float*)d_in[3];
    const float* ob2 = (const float*)d_in[4];
    const float* pW1 = (const float*)d_in[5];
    const float* pb1 = (const float*)d_in[6];
    const float* pW2 = (const float*)d_in[7];
    const float* pb2 = (const float*)d_in[8];
    const float* pW3 = (const float*)d_in[9];
    const float* pb3 = (const float*)d_in[10];
    const float* Wq  = (const float*)d_in[11];
    const float* bq  = (const float*)d_in[12];
    const float* Wk  = (const float*)d_in[13];
    const float* bk  = (const float*)d_in[14];
    const float* Wv  = (const float*)d_in[15];
    const float* bv  = (const float*)d_in[16];
    float*  out = (float*)d_out;
    float*  qkg = (float*)d_ws;
    float*  qbg = (float*)((char*)d_ws + QK_BYTES);
    __bf16* wp  = (__bf16*)((char*)d_ws + QK_BYTES + QB_BYTES);

    k_oth<<<BATCH / 32, 512, 0, stream>>>(obs, oW1, ob1, oW2, ob2, Wq, bq,
                                          Wk, bk, pW1, pW2, pW3,
                                          out, qkg, qbg, wp);
    k_obj<<<BATCH, 256, 0, stream>>>(obs, wp, pb1, pb2, pb3, qkg, qbg,
                                     bv, Wv, out);
}